// Round 19
// baseline (305.409 us; speedup 1.0000x reference)
//
#include <hip/hip_runtime.h>
#include <hip/hip_bf16.h>
#include <cstdint>

typedef __attribute__((ext_vector_type(4))) float f32x4;
typedef _Float16 f16x8 __attribute__((ext_vector_type(8)));
typedef _Float16 f16x4 __attribute__((ext_vector_type(4)));

#define BN_EPS 1e-5f

// ---------------- fp32 -> fp16 cast (only W, 4 MB) ----------------
__global__ __launch_bounds__(256)
void cast_f32_f16(const float* __restrict__ src, _Float16* __restrict__ dst, int n8) {
    int i = blockIdx.x * blockDim.x + threadIdx.x;
    if (i >= n8) return;
    const float4* s4 = (const float4*)src;
    float4 a = s4[2 * (size_t)i];
    float4 b = s4[2 * (size_t)i + 1];
    f16x8 h;
    h[0] = (_Float16)a.x; h[1] = (_Float16)a.y; h[2] = (_Float16)a.z; h[3] = (_Float16)a.w;
    h[4] = (_Float16)b.x; h[5] = (_Float16)b.y; h[6] = (_Float16)b.z; h[7] = (_Float16)b.w;
    *(f16x8*)(dst + 8 * (size_t)i) = h;
}

// async global->LDS, 16B per lane, wave-uniform LDS base (B path)
__device__ __forceinline__ void async16(const char* g, char* l) {
    __builtin_amdgcn_global_load_lds(
        (const __attribute__((address_space(1))) unsigned int*)(uintptr_t)g,
        (__attribute__((address_space(3))) unsigned int*)(uintptr_t)l,
        16, 0, 0);
}

// ====== 256x128 tile, 8 waves (4wr x 2wc, 64x64 each), BK=32 -> 2 BLOCKS/CU ======
// acc[4][4]=64 regs (r17 lesson: acc[8][4]=128 made 4-waves/SIMD impossible). Peak live
// ~120 <= 128 -> launch_bounds(512,4) gives 2 co-resident blocks (m114 desync overlap).
// LDS = A 2x16KB ([256][32] f16) + B 3x8KB ([128][32] f16) + red 4KB = 60KB.
// All staging/read patterns are r16's proven 0-conflict ones (same formulas).
// FIFO ledger per wave/tile {A=4 reg loads, B=1 async}, single rA slot:
//   entering kt: queue [A(kt+1)4, B(kt+1)1]
//   (a) cvt+write A(kt+1)   [compiler vmcnt(1)]
//   (b) A(kt+2)->rA  (c) B(kt+2) async  [queue: B(kt+1),A(kt+2)4,B(kt+2) = 6]
//   (d) 8 ds_read  (e) 16 MFMA (setprio)
//   (f) vmcnt(5) retires B(kt+1)  (g) lgkmcnt(0); barrier
// WAR: A-write@kt -> ABUF((kt+1)&1)=ABUF((kt-1)&1), reads drained at barrier kt-1.
//      B-async@kt -> BBUF((kt+2)%3)=BBUF((kt-1)%3), reads drained at barrier kt-1.
// Tails: kt=nt-2: no stages, (f) vmcnt(0); kt=nt-1: compute only, no barrier.

#define ABUF(t) (lds + ((t) & 1) * 16384)
#define BBUF(t) (lds + 32768 + ((t) % 3) * 8192)

__device__ __forceinline__ void cvtWrite(char* addr, const f32x4& v) {
    f16x4 h;
    h[0] = (_Float16)v[0]; h[1] = (_Float16)v[1];
    h[2] = (_Float16)v[2]; h[3] = (_Float16)v[3];
    *(f16x4*)addr = h;
}

template<int WAITN, bool STAGE, bool WRITEA, bool BAR>
__device__ __forceinline__ void ktile(
    int kt, char* lds, const float* aBase, size_t aRowStep,
    const char* b0, int widB,
    int aoff, int boff, const int (&wA)[4], f32x4 (&rA)[4],
    f32x4 (&acc)[4][4])
{
    // (a) cvt + ds_write A(kt+1)
    if (WRITEA) {
        char* ad = ABUF(kt + 1);
        #pragma unroll
        for (int j = 0; j < 4; ++j) cvtWrite(ad + wA[j], rA[j]);
    }
    // (b) A(kt+2) -> rA (slot just freed)  (c) B(kt+2) async
    if (STAGE) {
        #pragma unroll
        for (int j = 0; j < 4; ++j)
            rA[j] = *(const f32x4*)(aBase + j * aRowStep + (size_t)(kt + 2) * 32);
        async16(b0 + (size_t)(kt + 2) * 64, BBUF(kt + 2) + widB);
    }
    // (d) fragment reads
    f16x8 a[4], b[4];
    const char* ab = ABUF(kt);
    const char* bb = BBUF(kt);
    #pragma unroll
    for (int n = 0; n < 4; ++n) b[n] = *(const f16x8*)(bb + boff + n * 1024);
    #pragma unroll
    for (int m = 0; m < 4; ++m) a[m] = *(const f16x8*)(ab + aoff + m * 1024);
    // (e) MFMA
    __builtin_amdgcn_s_setprio(1);
    #pragma unroll
    for (int m = 0; m < 4; ++m)
        #pragma unroll
        for (int n = 0; n < 4; ++n)
            acc[m][n] = __builtin_amdgcn_mfma_f32_16x16x32_f16(a[m], b[n], acc[m][n], 0, 0, 0);
    __builtin_amdgcn_s_setprio(0);
    // (f,g)
    if (WAITN == 5)      { asm volatile("s_waitcnt vmcnt(5)" ::: "memory"); }
    else if (WAITN == 0) { asm volatile("s_waitcnt vmcnt(0)" ::: "memory"); }
    if (BAR) {
        asm volatile("s_waitcnt lgkmcnt(0)" ::: "memory");
        __builtin_amdgcn_s_barrier();
    }
}

__global__ __launch_bounds__(512, 4)
void gemm_gbn_kernel(const float* __restrict__ Af,
                     const _Float16* __restrict__ Bw,
                     const float* __restrict__ priors,
                     const float* __restrict__ gamma,
                     const float* __restrict__ beta,
                     _Float16* __restrict__ Zh,
                     int M, int N, int K)
{
    __shared__ __align__(16) char lds[57344];   // A 2x16KB + B 3x8KB = 56KB
    __shared__ float red[4][128][2];            // 4KB GBN partials (per-wr, per-col)

    const int tid  = threadIdx.x;
    const int lane = tid & 63;
    const int wid  = tid >> 6;     // 0..7
    const int wr   = wid >> 1;     // 0..3  (64-row slice; VB = wr pairs)
    const int wc   = wid & 1;      // 0..1  (64-col slice)
    const int fr   = lane & 15;
    const int kg   = lane >> 4;

    // XCD-aware bijective swizzle (1024 blocks, %8==0): 128 row-panels x 8 col-blocks
    const int bid = blockIdx.x;
    const int swz = (bid & 7) * 128 + (bid >> 3);
    const int row0 = (swz >> 3) * 256;
    const int col0 = (swz & 7) * 128;

    // ---- A fused-cast staging (r16's exact proven pattern for 256 rows) ----
    const float* aBase = Af + (size_t)(row0 + (tid >> 3)) * (size_t)K + (tid & 7) * 4;
    const size_t aRowStep = (size_t)64 * K;
    int wA[4];
    {
        const int sub = tid & 7;
        #pragma unroll
        for (int j = 0; j < 4; ++j) {
            const int r = (tid >> 3) + j * 64;
            wA[j] = r * 64 + (((sub >> 1) ^ ((r >> 1) & 3)) * 16) + (sub & 1) * 8;
        }
    }

    // ---- B staging (proven gload_lds path; 128 rows, 1 issue/wave/tile) ----
    const int bperm = ((tid & 3) ^ ((tid >> 3) & 3)) * 16;
    const char* b0 = (const char*)Bw + (size_t)(col0 + (tid >> 2)) * (size_t)K * 2 + bperm;
    const int widB = wid * 1024;

    // ---- fragment read offsets (measured-0-conflict swizzle) ----
    int aoff = (wr * 64 + fr) * 64 + kg * 16;
    aoff ^= ((aoff >> 7) & 3) << 4;
    int boff = (wc * 64 + fr) * 64 + kg * 16;
    boff ^= ((boff >> 7) & 3) << 4;

    f32x4 acc[4][4];
    #pragma unroll
    for (int m = 0; m < 4; ++m)
        #pragma unroll
        for (int n = 0; n < 4; ++n)
            acc[m][n] = (f32x4)0.0f;

    const int nt = K >> 5;   // 64 K-tiles of 32
    f32x4 rA[4];

    // ---- prologue: A(0), B(0), B(1); write A(0); A(1); vmcnt(5) [retires B(0)] ----
    #pragma unroll
    for (int j = 0; j < 4; ++j) rA[j] = *(const f32x4*)(aBase + j * aRowStep);
    async16(b0, BBUF(0) + widB);
    async16(b0 + 64, BBUF(1) + widB);
    #pragma unroll
    for (int j = 0; j < 4; ++j) cvtWrite(ABUF(0) + wA[j], rA[j]);   // waits A(0): vmcnt(2)
    #pragma unroll
    for (int j = 0; j < 4; ++j) rA[j] = *(const f32x4*)(aBase + j * aRowStep + 32);
    asm volatile("s_waitcnt vmcnt(5)" ::: "memory");   // retires B(0); B(1)+A(1) in flight
    asm volatile("s_waitcnt lgkmcnt(0)" ::: "memory");
    __builtin_amdgcn_s_barrier();

    for (int kt = 0; kt < nt - 2; ++kt)
        ktile<5, true,  true,  true >(kt, lds, aBase, aRowStep, b0, widB, aoff, boff, wA, rA, acc);
    ktile<0,  false, true,  true >(nt - 2, lds, aBase, aRowStep, b0, widB, aoff, boff, wA, rA, acc);
    ktile<-1, false, false, false>(nt - 1, lds, aBase, aRowStep, b0, widB, aoff, boff, wA, rA, acc);

    // ---- fused Ghost BatchNorm + priors epilogue (VB = wr pair; red via LDS) ----
    __syncthreads();
    #pragma unroll
    for (int n = 0; n < 4; ++n) {
        float s1 = 0.f, s2 = 0.f;
        #pragma unroll
        for (int m = 0; m < 4; ++m)
            #pragma unroll
            for (int j = 0; j < 4; ++j) {
                float v = acc[m][n][j];
                s1 += v; s2 += v * v;
            }
        s1 += __shfl_xor(s1, 16); s2 += __shfl_xor(s2, 16);
        s1 += __shfl_xor(s1, 32); s2 += __shfl_xor(s2, 32);
        if (lane < 16) {
            red[wr][wc * 64 + n * 16 + lane][0] = s1;
            red[wr][wc * 64 + n * 16 + lane][1] = s2;
        }
    }
    __syncthreads();

    const int vb = wr >> 1;            // virtual batch within block (0,1)
    const int rowb = row0 + wr * 64 + kg * 4;
    #pragma unroll
    for (int n = 0; n < 4; ++n) {
        const int c = wc * 64 + n * 16 + fr;
        float s1 = red[2 * vb][c][0] + red[2 * vb + 1][c][0];
        float s2 = red[2 * vb][c][1] + red[2 * vb + 1][c][1];
        float mean = s1 * (1.f / 128.f);
        float var  = s2 * (1.f / 128.f) - mean * mean;
        float rstd = rsqrtf(var + BN_EPS);
        float g = gamma[col0 + c] * rstd;
        float b = beta[col0 + c] - mean * g;
        #pragma unroll
        for (int m = 0; m < 4; ++m)
            #pragma unroll
            for (int j = 0; j < 4; ++j) {
                int r = rowb + m * 16 + j;
                size_t off = (size_t)r * N + col0 + c;
                Zh[off] = (_Float16)((acc[m][n][j] * g + b) * priors[off]);
            }
    }
}

// ---------------- sparsemax: one wave per row (1024), f16 input, exact Michelot ----------------
__device__ __forceinline__ float waveSum(float v) {
    #pragma unroll
    for (int off = 32; off > 0; off >>= 1) v += __shfl_xor(v, off);
    return v;
}

__global__ __launch_bounds__(256)
void sparsemax_kernel(const _Float16* __restrict__ Zh, float* __restrict__ Out) {
    const int lane = threadIdx.x & 63;
    const int wid  = threadIdx.x >> 6;
    const size_t row = (size_t)blockIdx.x * 4 + wid;
    const f16x8* zr = (const f16x8*)(Zh + row * 1024);

    float p[16];
    #pragma unroll
    for (int j = 0; j < 2; ++j) {
        f16x8 v = zr[lane * 2 + j];
        #pragma unroll
        for (int e = 0; e < 8; ++e) p[8 * j + e] = (float)v[e];
    }

    float s = 0.f;
    #pragma unroll
    for (int i = 0; i < 16; ++i) s += p[i];
    s = waveSum(s);

    float kc  = 1024.f;
    float tau = (s - 1.f) * (1.f / 1024.f);
    for (int it = 0; it < 64; ++it) {
        float s2 = 0.f, c2 = 0.f;
        #pragma unroll
        for (int i = 0; i < 16; ++i) {
            if (p[i] > tau) { s2 += p[i]; c2 += 1.f; }
        }
        s2 = waveSum(s2); c2 = waveSum(c2);
        if (c2 == kc) break;        // support stable -> tau exact
        kc = c2;
        tau = (s2 - 1.f) / c2;
    }

    float* outr = Out + row * 1024 + lane * 16;
    #pragma unroll
    for (int j = 0; j < 4; ++j) {
        float4 o;
        o.x = fmaxf(p[4 * j + 0] - tau, 0.f);
        o.y = fmaxf(p[4 * j + 1] - tau, 0.f);
        o.z = fmaxf(p[4 * j + 2] - tau, 0.f);
        o.w = fmaxf(p[4 * j + 3] - tau, 0.f);
        *(float4*)(outr + 4 * j) = o;
    }
}

extern "C" void kernel_launch(void* const* d_in, const int* in_sizes, int n_in,
                              void* d_out, int out_size, void* d_ws, size_t ws_size,
                              hipStream_t stream)
{
    const float* priors = (const float*)d_in[0];
    const float* feat   = (const float*)d_in[1];
    const float* W      = (const float*)d_in[2];
    const float* gamma  = (const float*)d_in[3];
    const float* beta   = (const float*)d_in[4];
    float* out = (float*)d_out;

    const int Nf = in_sizes[3];              // 1024
    const int Kf = in_sizes[2] / Nf;         // 2048
    const int Mr = in_sizes[1] / Kf;         // 32768

    _Float16* Wh = (_Float16*)d_ws;                                   // 4 MB
    _Float16* Zh = (_Float16*)((char*)d_ws + (size_t)Nf * Kf * 2);    // 64 MB

    {
        int n8 = Nf * (Kf / 8);
        cast_f32_f16<<<(n8 + 255) / 256, 256, 0, stream>>>(W, Wh, n8);
    }

    int nblk = (Mr / 256) * (Nf / 128);      // 1024, divisible by 8
    gemm_gbn_kernel<<<nblk, 512, 0, stream>>>(feat, Wh, priors, gamma, beta, Zh, Mr, Nf, Kf);

    sparsemax_kernel<<<Mr / 4, 256, 0, stream>>>(Zh, out);
}

// Round 20
// 275.280 us; speedup vs baseline: 1.1095x; 1.1095x over previous
//
#include <hip/hip_runtime.h>
#include <hip/hip_bf16.h>
#include <cstdint>

typedef __attribute__((ext_vector_type(4))) float f32x4;
typedef _Float16 f16x8 __attribute__((ext_vector_type(8)));
typedef _Float16 f16x4 __attribute__((ext_vector_type(4)));

#define BN_EPS 1e-5f

// ---------------- fp32 -> fp16 cast (only W, 4 MB) ----------------
__global__ __launch_bounds__(256)
void cast_f32_f16(const float* __restrict__ src, _Float16* __restrict__ dst, int n8) {
    int i = blockIdx.x * blockDim.x + threadIdx.x;
    if (i >= n8) return;
    const float4* s4 = (const float4*)src;
    float4 a = s4[2 * (size_t)i];
    float4 b = s4[2 * (size_t)i + 1];
    f16x8 h;
    h[0] = (_Float16)a.x; h[1] = (_Float16)a.y; h[2] = (_Float16)a.z; h[3] = (_Float16)a.w;
    h[4] = (_Float16)b.x; h[5] = (_Float16)b.y; h[6] = (_Float16)b.z; h[7] = (_Float16)b.w;
    *(f16x8*)(dst + 8 * (size_t)i) = h;
}

// async global->LDS, 16B per lane, wave-uniform LDS base (B path)
__device__ __forceinline__ void async16(const char* g, char* l) {
    __builtin_amdgcn_global_load_lds(
        (const __attribute__((address_space(1))) unsigned int*)(uintptr_t)g,
        (__attribute__((address_space(3))) unsigned int*)(uintptr_t)l,
        16, 0, 0);
}

// ====== 256x256, BK=64 (32 K-tiles): amortize per-tile dead time (r19 lesson) ======
// r19 proved occupancy is not the lever (2 blocks/CU, 41% occ -> SLOWER); the limiter is
// per-tile fixed cost (waits+barrier). BK=64 halves tile count: half the barriers/waits,
// 64 MFMA/wave per window, 2x longer bodies for the same prefetch depths.
// Buffers: A 2x32KB, B 2x32KB (each = two 16KB [256][32] f16 half-buffers, the proven
// 0-conflict geometry per half). All read/write/stage patterns = r16's proven formulas.
// FIFO ledger per wave/tile {A=8 reg loads, B=4 asyncs}:
//   entering kt: queue [A(kt+1) 8]
//   (c) B(kt+1) 4 asyncs -> BBUF((kt+1)&1)   [queue A8,B4]
//   (a) cvt+write A(kt+1) [compiler vmcnt(4) retires A(kt+1), leaves B(kt+1)]
//   (b) A(kt+2) 8 loads                      [queue B4,A8 = 12]
//   (d) per k-half: 12 ds_read; (e) 32 MFMA  (x2 halves, setprio)
//   (f) vmcnt(8) retires B(kt+1)  (g) lgkmcnt(0); barrier
// WAR: A-write@kt -> ABUF((kt+1)&1)=ABUF((kt-1)&1), reads drained before barrier@kt-1.
//      B-async@kt -> BBUF((kt+1)&1), reads@kt-1 drained before barrier@kt-1. Safe.
// Tails: kt=nt-2: STAGEA off, vmcnt(0); kt=nt-1: compute only.

#define ABUF(t) (lds + ((t) & 1) * 32768)
#define BBUF(t) (lds + 65536 + ((t) & 1) * 32768)

__device__ __forceinline__ void cvtWrite(char* addr, const f32x4& v) {
    f16x4 h;
    h[0] = (_Float16)v[0]; h[1] = (_Float16)v[1];
    h[2] = (_Float16)v[2]; h[3] = (_Float16)v[3];
    *(f16x4*)addr = h;
}

template<int WAITN, bool STAGEA, bool STAGEB, bool WRITEA, bool BAR>
__device__ __forceinline__ void ktile(
    int kt, char* lds, const float* aBase, size_t aRowStep,
    const char* b0, const char* b1, int widB,
    int aoff, int boff, const int (&wA)[4], f32x4 (&rA)[8],
    f32x4 (&acc)[8][4])
{
    // (c) B(kt+1): 4 asyncs (two k-halves x two row-chunks)
    if (STAGEB) {
        const size_t cb = (size_t)(kt + 1) * 128;
        char* d = BBUF(kt + 1);
        async16(b0 + cb,      d + widB);
        async16(b1 + cb,      d + 8192 + widB);
        async16(b0 + cb + 64, d + 16384 + widB);
        async16(b1 + cb + 64, d + 24576 + widB);
    }
    // (a) cvt + ds_write A(kt+1) (both halves)
    if (WRITEA) {
        char* ad = ABUF(kt + 1);
        #pragma unroll
        for (int h = 0; h < 2; ++h)
            #pragma unroll
            for (int j = 0; j < 4; ++j)
                cvtWrite(ad + h * 16384 + wA[j], rA[h * 4 + j]);
    }
    // (b) A(kt+2) -> rA
    if (STAGEA) {
        #pragma unroll
        for (int h = 0; h < 2; ++h)
            #pragma unroll
            for (int j = 0; j < 4; ++j)
                rA[h * 4 + j] = *(const f32x4*)(aBase + j * aRowStep + (size_t)(kt + 2) * 64 + h * 32);
    }
    // (d,e) two k-halves: 12 ds_read + 32 MFMA each
    #pragma unroll
    for (int h = 0; h < 2; ++h) {
        f16x8 a[8], b[4];
        const char* ab = ABUF(kt) + h * 16384;
        const char* bb = BBUF(kt) + h * 16384;
        #pragma unroll
        for (int n = 0; n < 4; ++n) b[n] = *(const f16x8*)(bb + boff + n * 1024);
        #pragma unroll
        for (int m = 0; m < 8; ++m) a[m] = *(const f16x8*)(ab + aoff + m * 1024);
        __builtin_amdgcn_s_setprio(1);
        #pragma unroll
        for (int m = 0; m < 8; ++m)
            #pragma unroll
            for (int n = 0; n < 4; ++n)
                acc[m][n] = __builtin_amdgcn_mfma_f32_16x16x32_f16(a[m], b[n], acc[m][n], 0, 0, 0);
        __builtin_amdgcn_s_setprio(0);
    }
    // (f,g)
    if (WAITN == 8)      { asm volatile("s_waitcnt vmcnt(8)" ::: "memory"); }
    else if (WAITN == 0) { asm volatile("s_waitcnt vmcnt(0)" ::: "memory"); }
    if (BAR) {
        asm volatile("s_waitcnt lgkmcnt(0)" ::: "memory");
        __builtin_amdgcn_s_barrier();
    }
}

__global__ __launch_bounds__(512, 2)
void gemm_gbn_kernel(const float* __restrict__ Af,
                     const _Float16* __restrict__ Bw,
                     const float* __restrict__ priors,
                     const float* __restrict__ gamma,
                     const float* __restrict__ beta,
                     _Float16* __restrict__ Zh,
                     int M, int N, int K)
{
    __shared__ __align__(16) char lds[131072];   // A 2x32KB + B 2x32KB

    const int tid  = threadIdx.x;
    const int lane = tid & 63;
    const int wid  = tid >> 6;     // 0..7
    const int wr   = wid >> 2;     // 0..1  (128-row half == one virtual batch)
    const int wc   = wid & 3;      // 0..3  (64-col slice)
    const int fr   = lane & 15;
    const int kg   = lane >> 4;

    // XCD-aware bijective swizzle (512 blocks, %8==0)
    const int bid = blockIdx.x;
    const int swz = (bid & 7) * 64 + (bid >> 3);
    const int row0 = (swz >> 2) * 256;
    const int col0 = (swz & 3) * 256;

    // ---- A fused-cast staging: load (h,j) covers row (tid>>3)+j*64, k-half h, granule tid&7 ----
    const float* aBase = Af + (size_t)(row0 + (tid >> 3)) * (size_t)K + (tid & 7) * 4;
    const size_t aRowStep = (size_t)64 * K;
    int wA[4];
    {
        const int sub = tid & 7;
        #pragma unroll
        for (int j = 0; j < 4; ++j) {
            const int r = (tid >> 3) + j * 64;
            wA[j] = r * 64 + (((sub >> 1) ^ ((r >> 1) & 3)) * 16) + (sub & 1) * 8;
        }
    }

    // ---- B staging (proven gload_lds path) ----
    const int bperm = ((tid & 3) ^ ((tid >> 3) & 3)) * 16;
    const char* b0 = (const char*)Bw + (size_t)(col0 + (tid >> 2)) * (size_t)K * 2 + bperm;
    const char* b1 = b0 + (size_t)128 * K * 2;
    const int widB = wid * 1024;

    // ---- fragment read offsets (within 16KB half-buffer; measured-0-conflict swizzle) ----
    int aoff = (wr * 128 + fr) * 64 + kg * 16;
    aoff ^= ((aoff >> 7) & 3) << 4;
    int boff = (wc * 64 + fr) * 64 + kg * 16;
    boff ^= ((boff >> 7) & 3) << 4;

    f32x4 acc[8][4];
    #pragma unroll
    for (int m = 0; m < 8; ++m)
        #pragma unroll
        for (int n = 0; n < 4; ++n)
            acc[m][n] = (f32x4)0.0f;

    const int nt = K >> 6;   // 32 K-tiles of 64
    f32x4 rA[8];

    // ---- prologue: A(0); B(0); cvt+write A(0) [vmcnt(4)]; A(1); vmcnt(8) [retires B(0)] ----
    #pragma unroll
    for (int h = 0; h < 2; ++h)
        #pragma unroll
        for (int j = 0; j < 4; ++j)
            rA[h * 4 + j] = *(const f32x4*)(aBase + j * aRowStep + h * 32);
    {
        char* d = BBUF(0);
        async16(b0,      d + widB);
        async16(b1,      d + 8192 + widB);
        async16(b0 + 64, d + 16384 + widB);
        async16(b1 + 64, d + 24576 + widB);
    }
    #pragma unroll
    for (int h = 0; h < 2; ++h)
        #pragma unroll
        for (int j = 0; j < 4; ++j)
            cvtWrite(ABUF(0) + h * 16384 + wA[j], rA[h * 4 + j]);   // waits A(0): vmcnt(4)
    #pragma unroll
    for (int h = 0; h < 2; ++h)
        #pragma unroll
        for (int j = 0; j < 4; ++j)
            rA[h * 4 + j] = *(const f32x4*)(aBase + j * aRowStep + 64 + h * 32);
    asm volatile("s_waitcnt vmcnt(8)" ::: "memory");   // retires B(0); A(1) in flight
    asm volatile("s_waitcnt lgkmcnt(0)" ::: "memory");
    __builtin_amdgcn_s_barrier();

    for (int kt = 0; kt < nt - 2; ++kt)
        ktile<8, true,  true,  true,  true >(kt, lds, aBase, aRowStep, b0, b1, widB, aoff, boff, wA, rA, acc);
    ktile<0,  false, true,  true,  true >(nt - 2, lds, aBase, aRowStep, b0, b1, widB, aoff, boff, wA, rA, acc);
    ktile<-1, false, false, false, false>(nt - 1, lds, aBase, aRowStep, b0, b1, widB, aoff, boff, wA, rA, acc);

    // ---- fused Ghost BatchNorm + priors epilogue (wave-local; z written f16) ----
    #pragma unroll
    for (int n = 0; n < 4; ++n) {
        float s1 = 0.f, s2 = 0.f;
        #pragma unroll
        for (int m = 0; m < 8; ++m)
            #pragma unroll
            for (int j = 0; j < 4; ++j) {
                float v = acc[m][n][j];
                s1 += v; s2 += v * v;
            }
        s1 += __shfl_xor(s1, 16); s2 += __shfl_xor(s2, 16);
        s1 += __shfl_xor(s1, 32); s2 += __shfl_xor(s2, 32);
        float mean = s1 * (1.f / 128.f);
        float var  = s2 * (1.f / 128.f) - mean * mean;
        float rstd = rsqrtf(var + BN_EPS);
        const int c = col0 + wc * 64 + n * 16 + fr;
        float g = gamma[c] * rstd;
        float b = beta[c] - mean * g;
        #pragma unroll
        for (int m = 0; m < 8; ++m)
            #pragma unroll
            for (int j = 0; j < 4; ++j) {
                int r = row0 + wr * 128 + m * 16 + kg * 4 + j;
                size_t off = (size_t)r * N + c;
                Zh[off] = (_Float16)((acc[m][n][j] * g + b) * priors[off]);
            }
    }
}

// ---------------- sparsemax: one wave per row (1024), f16 input, exact Michelot ----------------
__device__ __forceinline__ float waveSum(float v) {
    #pragma unroll
    for (int off = 32; off > 0; off >>= 1) v += __shfl_xor(v, off);
    return v;
}

__global__ __launch_bounds__(256)
void sparsemax_kernel(const _Float16* __restrict__ Zh, float* __restrict__ Out) {
    const int lane = threadIdx.x & 63;
    const int wid  = threadIdx.x >> 6;
    const size_t row = (size_t)blockIdx.x * 4 + wid;
    const f16x8* zr = (const f16x8*)(Zh + row * 1024);

    float p[16];
    #pragma unroll
    for (int j = 0; j < 2; ++j) {
        f16x8 v = zr[lane * 2 + j];
        #pragma unroll
        for (int e = 0; e < 8; ++e) p[8 * j + e] = (float)v[e];
    }

    float s = 0.f;
    #pragma unroll
    for (int i = 0; i < 16; ++i) s += p[i];
    s = waveSum(s);

    float kc  = 1024.f;
    float tau = (s - 1.f) * (1.f / 1024.f);
    for (int it = 0; it < 64; ++it) {
        float s2 = 0.f, c2 = 0.f;
        #pragma unroll
        for (int i = 0; i < 16; ++i) {
            if (p[i] > tau) { s2 += p[i]; c2 += 1.f; }
        }
        s2 = waveSum(s2); c2 = waveSum(c2);
        if (c2 == kc) break;        // support stable -> tau exact
        kc = c2;
        tau = (s2 - 1.f) / c2;
    }

    float* outr = Out + row * 1024 + lane * 16;
    #pragma unroll
    for (int j = 0; j < 4; ++j) {
        float4 o;
        o.x = fmaxf(p[4 * j + 0] - tau, 0.f);
        o.y = fmaxf(p[4 * j + 1] - tau, 0.f);
        o.z = fmaxf(p[4 * j + 2] - tau, 0.f);
        o.w = fmaxf(p[4 * j + 3] - tau, 0.f);
        *(float4*)(outr + 4 * j) = o;
    }
}

extern "C" void kernel_launch(void* const* d_in, const int* in_sizes, int n_in,
                              void* d_out, int out_size, void* d_ws, size_t ws_size,
                              hipStream_t stream)
{
    const float* priors = (const float*)d_in[0];
    const float* feat   = (const float*)d_in[1];
    const float* W      = (const float*)d_in[2];
    const float* gamma  = (const float*)d_in[3];
    const float* beta   = (const float*)d_in[4];
    float* out = (float*)d_out;

    const int Nf = in_sizes[3];              // 1024
    const int Kf = in_sizes[2] / Nf;         // 2048
    const int Mr = in_sizes[1] / Kf;         // 32768

    _Float16* Wh = (_Float16*)d_ws;                                   // 4 MB
    _Float16* Zh = (_Float16*)((char*)d_ws + (size_t)Nf * Kf * 2);    // 64 MB

    {
        int n8 = Nf * (Kf / 8);
        cast_f32_f16<<<(n8 + 255) / 256, 256, 0, stream>>>(W, Wh, n8);
    }

    int nblk = (Mr / 256) * (Nf / 256);      // 512, divisible by 8
    gemm_gbn_kernel<<<nblk, 512, 0, stream>>>(feat, Wh, priors, gamma, beta, Zh, Mr, Nf, Kf);

    sparsemax_kernel<<<Mr / 4, 256, 0, stream>>>(Zh, out);
}

// Round 21
// 271.206 us; speedup vs baseline: 1.1261x; 1.0150x over previous
//
#include <hip/hip_runtime.h>
#include <hip/hip_bf16.h>
#include <cstdint>

typedef __attribute__((ext_vector_type(4))) float f32x4;
typedef _Float16 f16x8 __attribute__((ext_vector_type(8)));
typedef _Float16 f16x4 __attribute__((ext_vector_type(4)));

#define BN_EPS 1e-5f

// ---------------- fp32 -> fp16 cast (only W, 4 MB) ----------------
__global__ __launch_bounds__(256)
void cast_f32_f16(const float* __restrict__ src, _Float16* __restrict__ dst, int n8) {
    int i = blockIdx.x * blockDim.x + threadIdx.x;
    if (i >= n8) return;
    const float4* s4 = (const float4*)src;
    float4 a = s4[2 * (size_t)i];
    float4 b = s4[2 * (size_t)i + 1];
    f16x8 h;
    h[0] = (_Float16)a.x; h[1] = (_Float16)a.y; h[2] = (_Float16)a.z; h[3] = (_Float16)a.w;
    h[4] = (_Float16)b.x; h[5] = (_Float16)b.y; h[6] = (_Float16)b.z; h[7] = (_Float16)b.w;
    *(f16x8*)(dst + 8 * (size_t)i) = h;
}

// async global->LDS, 16B per lane, wave-uniform LDS base (B path)
__device__ __forceinline__ void async16(const char* g, char* l) {
    __builtin_amdgcn_global_load_lds(
        (const __attribute__((address_space(1))) unsigned int*)(uintptr_t)g,
        (__attribute__((address_space(3))) unsigned int*)(uintptr_t)l,
        16, 0, 0);
}

// ====== 256x256, BK=64 (32 K-tiles), fused A-cast — r20 best (275.3us) minus setprio ======
// setprio removal basis: m190 within-probe A/B measured s_setprio ~0 to NEGATIVE on
// lockstep (non-phase-split) GEMM, which this is. Everything else identical to r20.
// Buffers: A 2x32KB, B 2x32KB (each = two 16KB [256][32] f16 half-buffers, proven
// 0-conflict geometry). FIFO ledger per wave/tile {A=8 reg loads, B=4 asyncs}:
//   entering kt: queue [A(kt+1) 8]
//   (c) B(kt+1) 4 asyncs -> BBUF((kt+1)&1)   [queue A8,B4]
//   (a) cvt+write A(kt+1) [compiler vmcnt(4) retires A(kt+1), leaves B(kt+1)]
//   (b) A(kt+2) 8 loads                      [queue B4,A8 = 12]
//   (d) per k-half: 12 ds_read; (e) 32 MFMA  (x2 halves)
//   (f) vmcnt(8) retires B(kt+1) (exact: queue=[B(kt+1)4, A(kt+2)8])  (g) lgkm0; barrier
// WAR: A-write@kt -> ABUF((kt+1)&1)=ABUF((kt-1)&1), reads drained before barrier@kt-1.
//      B-async@kt -> BBUF((kt+1)&1), reads@kt-1 drained before barrier@kt-1. Safe.
// Tails: kt=nt-2: STAGEA off, vmcnt(0); kt=nt-1: compute only.
// r17 lesson: min-waves/EU stays 2 — acc[8][4]=128 regs makes 4/EU spill catastrophically.

#define ABUF(t) (lds + ((t) & 1) * 32768)
#define BBUF(t) (lds + 65536 + ((t) & 1) * 32768)

__device__ __forceinline__ void cvtWrite(char* addr, const f32x4& v) {
    f16x4 h;
    h[0] = (_Float16)v[0]; h[1] = (_Float16)v[1];
    h[2] = (_Float16)v[2]; h[3] = (_Float16)v[3];
    *(f16x4*)addr = h;
}

template<int WAITN, bool STAGEA, bool STAGEB, bool WRITEA, bool BAR>
__device__ __forceinline__ void ktile(
    int kt, char* lds, const float* aBase, size_t aRowStep,
    const char* b0, const char* b1, int widB,
    int aoff, int boff, const int (&wA)[4], f32x4 (&rA)[8],
    f32x4 (&acc)[8][4])
{
    // (c) B(kt+1): 4 asyncs (two k-halves x two row-chunks)
    if (STAGEB) {
        const size_t cb = (size_t)(kt + 1) * 128;
        char* d = BBUF(kt + 1);
        async16(b0 + cb,      d + widB);
        async16(b1 + cb,      d + 8192 + widB);
        async16(b0 + cb + 64, d + 16384 + widB);
        async16(b1 + cb + 64, d + 24576 + widB);
    }
    // (a) cvt + ds_write A(kt+1) (both halves)
    if (WRITEA) {
        char* ad = ABUF(kt + 1);
        #pragma unroll
        for (int h = 0; h < 2; ++h)
            #pragma unroll
            for (int j = 0; j < 4; ++j)
                cvtWrite(ad + h * 16384 + wA[j], rA[h * 4 + j]);
    }
    // (b) A(kt+2) -> rA
    if (STAGEA) {
        #pragma unroll
        for (int h = 0; h < 2; ++h)
            #pragma unroll
            for (int j = 0; j < 4; ++j)
                rA[h * 4 + j] = *(const f32x4*)(aBase + j * aRowStep + (size_t)(kt + 2) * 64 + h * 32);
    }
    // (d,e) two k-halves: 12 ds_read + 32 MFMA each
    #pragma unroll
    for (int h = 0; h < 2; ++h) {
        f16x8 a[8], b[4];
        const char* ab = ABUF(kt) + h * 16384;
        const char* bb = BBUF(kt) + h * 16384;
        #pragma unroll
        for (int n = 0; n < 4; ++n) b[n] = *(const f16x8*)(bb + boff + n * 1024);
        #pragma unroll
        for (int m = 0; m < 8; ++m) a[m] = *(const f16x8*)(ab + aoff + m * 1024);
        #pragma unroll
        for (int m = 0; m < 8; ++m)
            #pragma unroll
            for (int n = 0; n < 4; ++n)
                acc[m][n] = __builtin_amdgcn_mfma_f32_16x16x32_f16(a[m], b[n], acc[m][n], 0, 0, 0);
    }
    // (f,g)
    if (WAITN == 8)      { asm volatile("s_waitcnt vmcnt(8)" ::: "memory"); }
    else if (WAITN == 0) { asm volatile("s_waitcnt vmcnt(0)" ::: "memory"); }
    if (BAR) {
        asm volatile("s_waitcnt lgkmcnt(0)" ::: "memory");
        __builtin_amdgcn_s_barrier();
    }
}

__global__ __launch_bounds__(512, 2)
void gemm_gbn_kernel(const float* __restrict__ Af,
                     const _Float16* __restrict__ Bw,
                     const float* __restrict__ priors,
                     const float* __restrict__ gamma,
                     const float* __restrict__ beta,
                     _Float16* __restrict__ Zh,
                     int M, int N, int K)
{
    __shared__ __align__(16) char lds[131072];   // A 2x32KB + B 2x32KB

    const int tid  = threadIdx.x;
    const int lane = tid & 63;
    const int wid  = tid >> 6;     // 0..7
    const int wr   = wid >> 2;     // 0..1  (128-row half == one virtual batch)
    const int wc   = wid & 3;      // 0..3  (64-col slice)
    const int fr   = lane & 15;
    const int kg   = lane >> 4;

    // XCD-aware bijective swizzle (512 blocks, %8==0)
    const int bid = blockIdx.x;
    const int swz = (bid & 7) * 64 + (bid >> 3);
    const int row0 = (swz >> 2) * 256;
    const int col0 = (swz & 3) * 256;

    // ---- A fused-cast staging: load (h,j) covers row (tid>>3)+j*64, k-half h, granule tid&7 ----
    const float* aBase = Af + (size_t)(row0 + (tid >> 3)) * (size_t)K + (tid & 7) * 4;
    const size_t aRowStep = (size_t)64 * K;
    int wA[4];
    {
        const int sub = tid & 7;
        #pragma unroll
        for (int j = 0; j < 4; ++j) {
            const int r = (tid >> 3) + j * 64;
            wA[j] = r * 64 + (((sub >> 1) ^ ((r >> 1) & 3)) * 16) + (sub & 1) * 8;
        }
    }

    // ---- B staging (proven gload_lds path) ----
    const int bperm = ((tid & 3) ^ ((tid >> 3) & 3)) * 16;
    const char* b0 = (const char*)Bw + (size_t)(col0 + (tid >> 2)) * (size_t)K * 2 + bperm;
    const char* b1 = b0 + (size_t)128 * K * 2;
    const int widB = wid * 1024;

    // ---- fragment read offsets (within 16KB half-buffer; measured-0-conflict swizzle) ----
    int aoff = (wr * 128 + fr) * 64 + kg * 16;
    aoff ^= ((aoff >> 7) & 3) << 4;
    int boff = (wc * 64 + fr) * 64 + kg * 16;
    boff ^= ((boff >> 7) & 3) << 4;

    f32x4 acc[8][4];
    #pragma unroll
    for (int m = 0; m < 8; ++m)
        #pragma unroll
        for (int n = 0; n < 4; ++n)
            acc[m][n] = (f32x4)0.0f;

    const int nt = K >> 6;   // 32 K-tiles of 64
    f32x4 rA[8];

    // ---- prologue: A(0); B(0); cvt+write A(0) [vmcnt(4)]; A(1); vmcnt(8) [retires B(0)] ----
    #pragma unroll
    for (int h = 0; h < 2; ++h)
        #pragma unroll
        for (int j = 0; j < 4; ++j)
            rA[h * 4 + j] = *(const f32x4*)(aBase + j * aRowStep + h * 32);
    {
        char* d = BBUF(0);
        async16(b0,      d + widB);
        async16(b1,      d + 8192 + widB);
        async16(b0 + 64, d + 16384 + widB);
        async16(b1 + 64, d + 24576 + widB);
    }
    #pragma unroll
    for (int h = 0; h < 2; ++h)
        #pragma unroll
        for (int j = 0; j < 4; ++j)
            cvtWrite(ABUF(0) + h * 16384 + wA[j], rA[h * 4 + j]);   // waits A(0): vmcnt(4)
    #pragma unroll
    for (int h = 0; h < 2; ++h)
        #pragma unroll
        for (int j = 0; j < 4; ++j)
            rA[h * 4 + j] = *(const f32x4*)(aBase + j * aRowStep + 64 + h * 32);
    asm volatile("s_waitcnt vmcnt(8)" ::: "memory");   // retires B(0); A(1) in flight
    asm volatile("s_waitcnt lgkmcnt(0)" ::: "memory");
    __builtin_amdgcn_s_barrier();

    for (int kt = 0; kt < nt - 2; ++kt)
        ktile<8, true,  true,  true,  true >(kt, lds, aBase, aRowStep, b0, b1, widB, aoff, boff, wA, rA, acc);
    ktile<0,  false, true,  true,  true >(nt - 2, lds, aBase, aRowStep, b0, b1, widB, aoff, boff, wA, rA, acc);
    ktile<-1, false, false, false, false>(nt - 1, lds, aBase, aRowStep, b0, b1, widB, aoff, boff, wA, rA, acc);

    // ---- fused Ghost BatchNorm + priors epilogue (wave-local; z written f16) ----
    #pragma unroll
    for (int n = 0; n < 4; ++n) {
        float s1 = 0.f, s2 = 0.f;
        #pragma unroll
        for (int m = 0; m < 8; ++m)
            #pragma unroll
            for (int j = 0; j < 4; ++j) {
                float v = acc[m][n][j];
                s1 += v; s2 += v * v;
            }
        s1 += __shfl_xor(s1, 16); s2 += __shfl_xor(s2, 16);
        s1 += __shfl_xor(s1, 32); s2 += __shfl_xor(s2, 32);
        float mean = s1 * (1.f / 128.f);
        float var  = s2 * (1.f / 128.f) - mean * mean;
        float rstd = rsqrtf(var + BN_EPS);
        const int c = col0 + wc * 64 + n * 16 + fr;
        float g = gamma[c] * rstd;
        float b = beta[c] - mean * g;
        #pragma unroll
        for (int m = 0; m < 8; ++m)
            #pragma unroll
            for (int j = 0; j < 4; ++j) {
                int r = row0 + wr * 128 + m * 16 + kg * 4 + j;
                size_t off = (size_t)r * N + c;
                Zh[off] = (_Float16)((acc[m][n][j] * g + b) * priors[off]);
            }
    }
}

// ---------------- sparsemax: one wave per row (1024), f16 input, exact Michelot ----------------
__device__ __forceinline__ float waveSum(float v) {
    #pragma unroll
    for (int off = 32; off > 0; off >>= 1) v += __shfl_xor(v, off);
    return v;
}

__global__ __launch_bounds__(256)
void sparsemax_kernel(const _Float16* __restrict__ Zh, float* __restrict__ Out) {
    const int lane = threadIdx.x & 63;
    const int wid  = threadIdx.x >> 6;
    const size_t row = (size_t)blockIdx.x * 4 + wid;
    const f16x8* zr = (const f16x8*)(Zh + row * 1024);

    float p[16];
    #pragma unroll
    for (int j = 0; j < 2; ++j) {
        f16x8 v = zr[lane * 2 + j];
        #pragma unroll
        for (int e = 0; e < 8; ++e) p[8 * j + e] = (float)v[e];
    }

    float s = 0.f;
    #pragma unroll
    for (int i = 0; i < 16; ++i) s += p[i];
    s = waveSum(s);

    float kc  = 1024.f;
    float tau = (s - 1.f) * (1.f / 1024.f);
    for (int it = 0; it < 64; ++it) {
        float s2 = 0.f, c2 = 0.f;
        #pragma unroll
        for (int i = 0; i < 16; ++i) {
            if (p[i] > tau) { s2 += p[i]; c2 += 1.f; }
        }
        s2 = waveSum(s2); c2 = waveSum(c2);
        if (c2 == kc) break;        // support stable -> tau exact
        kc = c2;
        tau = (s2 - 1.f) / c2;
    }

    float* outr = Out + row * 1024 + lane * 16;
    #pragma unroll
    for (int j = 0; j < 4; ++j) {
        float4 o;
        o.x = fmaxf(p[4 * j + 0] - tau, 0.f);
        o.y = fmaxf(p[4 * j + 1] - tau, 0.f);
        o.z = fmaxf(p[4 * j + 2] - tau, 0.f);
        o.w = fmaxf(p[4 * j + 3] - tau, 0.f);
        *(float4*)(outr + 4 * j) = o;
    }
}

extern "C" void kernel_launch(void* const* d_in, const int* in_sizes, int n_in,
                              void* d_out, int out_size, void* d_ws, size_t ws_size,
                              hipStream_t stream)
{
    const float* priors = (const float*)d_in[0];
    const float* feat   = (const float*)d_in[1];
    const float* W      = (const float*)d_in[2];
    const float* gamma  = (const float*)d_in[3];
    const float* beta   = (const float*)d_in[4];
    float* out = (float*)d_out;

    const int Nf = in_sizes[3];              // 1024
    const int Kf = in_sizes[2] / Nf;         // 2048
    const int Mr = in_sizes[1] / Kf;         // 32768

    _Float16* Wh = (_Float16*)d_ws;                                   // 4 MB
    _Float16* Zh = (_Float16*)((char*)d_ws + (size_t)Nf * Kf * 2);    // 64 MB

    {
        int n8 = Nf * (Kf / 8);
        cast_f32_f16<<<(n8 + 255) / 256, 256, 0, stream>>>(W, Wh, n8);
    }

    int nblk = (Mr / 256) * (Nf / 256);      // 512, divisible by 8
    gemm_gbn_kernel<<<nblk, 512, 0, stream>>>(feat, Wh, priors, gamma, beta, Zh, Mr, Nf, Kf);

    sparsemax_kernel<<<Mr / 4, 256, 0, stream>>>(Zh, out);
}